// Round 8
// baseline (528.193 us; speedup 1.0000x reference)
//
#include <hip/hip_runtime.h>
#include <math.h>

#define NN 100000
#define NE 640000
#define MPAD 100032   // NN rounded up to 64
#define NBLK 98       // ceil(NN / 1024)

typedef __bf16 bf16_t;
typedef bf16_t bf16x8 __attribute__((ext_vector_type(8)));
typedef float  f32x4  __attribute__((ext_vector_type(4)));

// ================= CSR build =================

__global__ __launch_bounds__(256) void k_hist(const int* __restrict__ dst,
                                              int* __restrict__ deg) {
    int e = blockIdx.x * 256 + threadIdx.x;
    if (e < NE) atomicAdd(&deg[dst[e]], 1);
}

__global__ __launch_bounds__(1024) void k_bsum(const int* __restrict__ deg,
                                               int* __restrict__ bsum) {
    __shared__ int warr[16];
    int t = threadIdx.x;
    int i = blockIdx.x * 1024 + t;
    int v = (i < NN) ? deg[i] : 0;
    int lane = t & 63, wid = t >> 6;
    #pragma unroll
    for (int off = 32; off > 0; off >>= 1) v += __shfl_xor(v, off, 64);
    if (lane == 0) warr[wid] = v;
    __syncthreads();
    if (t < 16) {
        int s = warr[t];
        #pragma unroll
        for (int off = 8; off > 0; off >>= 1) s += __shfl_xor(s, off, 64);
        if (t == 0) bsum[blockIdx.x] = s;
    }
}

__global__ __launch_bounds__(64) void k_bscan(const int* __restrict__ bsum,
        int* __restrict__ boff, int* __restrict__ rowptr) {
    int lane = threadIdx.x;
    int carry = 0;
    for (int base = 0; base < NBLK; base += 64) {
        int i = base + lane;
        int v = (i < NBLK) ? bsum[i] : 0;
        int s = v;
        #pragma unroll
        for (int off = 1; off < 64; off <<= 1) {
            int u = __shfl_up(s, off, 64);
            if (lane >= off) s += u;
        }
        if (i < NBLK) boff[i] = carry + s - v;
        carry += __shfl(s, 63, 64);
    }
    if (lane == 0) rowptr[NN] = NE;
}

__global__ __launch_bounds__(1024) void k_scan2(const int* __restrict__ deg,
        const int* __restrict__ boff, int* __restrict__ rowptr,
        int* __restrict__ cursor) {
    __shared__ int wsum[16];
    __shared__ int woff[16];
    int t = threadIdx.x;
    int lane = t & 63, wid = t >> 6;
    int i = blockIdx.x * 1024 + t;
    int v = (i < NN) ? deg[i] : 0;
    int s = v;
    #pragma unroll
    for (int off = 1; off < 64; off <<= 1) {
        int u = __shfl_up(s, off, 64);
        if (lane >= off) s += u;
    }
    if (lane == 63) wsum[wid] = s;
    __syncthreads();
    if (wid == 0) {
        int ws = (lane < 16) ? wsum[lane] : 0;
        #pragma unroll
        for (int off = 1; off < 16; off <<= 1) {
            int u = __shfl_up(ws, off, 64);
            if (lane >= off) ws += u;
        }
        if (lane < 16) woff[lane] = ws;
    }
    __syncthreads();
    if (i < NN) {
        int excl = boff[blockIdx.x] + (s - v) + (wid ? woff[wid - 1] : 0);
        rowptr[i] = excl;
        cursor[i] = excl;
    }
}

__global__ __launch_bounds__(256) void k_fill(const int* __restrict__ src,
        const int* __restrict__ dst, int* __restrict__ cursor,
        int* __restrict__ csr) {
    int e = blockIdx.x * 256 + threadIdx.x;
    if (e >= NE) return;
    int p = atomicAdd(&cursor[dst[e]], 1);
    csr[p] = src[e];
}

// ================= weight split (f32 -> hi/lo bf16) =================

__global__ __launch_bounds__(256) void k_split_w1(const float* __restrict__ W1l,
        const float* __restrict__ W1r, bf16_t* __restrict__ Wh,
        bf16_t* __restrict__ Wl) {
    int j = blockIdx.x, t = threadIdx.x;
    float f = (t < 128) ? W1l[j * 128 + t] : W1r[j * 128 + (t - 128)];
    bf16_t h = (bf16_t)f;
    bf16_t l = (bf16_t)(f - (float)h);
    Wh[j * 256 + t] = h;
    Wl[j * 256 + t] = l;
}

__global__ __launch_bounds__(256) void k_split_w2(const float* __restrict__ W2l,
        const float* __restrict__ W2r, bf16_t* __restrict__ Wh,
        bf16_t* __restrict__ Wl) {
    int j = blockIdx.x, t = threadIdx.x;
    float f = (j < 128) ? W2l[j * 256 + t] : W2r[(j - 128) * 256 + t];
    bf16_t h = (bf16_t)f;
    bf16_t l = (bf16_t)(f - (float)h);
    Wh[j * 256 + t] = h;
    Wl[j * 256 + t] = l;
}

// ================= gather-mean for layer 1 (f32, 128 wide) =================

__global__ __launch_bounds__(256) void k_gather128s(const float* __restrict__ feat,
        const int* __restrict__ rowptr, const int* __restrict__ csr,
        float* __restrict__ agg) {
    int tid = blockIdx.x * 256 + threadIdx.x;
    int node = tid >> 5;
    if (node >= NN) return;
    int lane4 = (tid & 31) << 2;
    int beg = rowptr[node], end = rowptr[node + 1];
    float4 acc = make_float4(0.f, 0.f, 0.f, 0.f);
    int e = beg;
    for (; e + 1 < end; e += 2) {
        int s0 = csr[e], s1 = csr[e + 1];
        float4 v0 = *(const float4*)(feat + (size_t)s0 * 128 + lane4);
        float4 v1 = *(const float4*)(feat + (size_t)s1 * 128 + lane4);
        acc.x += v0.x + v1.x; acc.y += v0.y + v1.y;
        acc.z += v0.z + v1.z; acc.w += v0.w + v1.w;
    }
    if (e < end) {
        int s0 = csr[e];
        float4 v0 = *(const float4*)(feat + (size_t)s0 * 128 + lane4);
        acc.x += v0.x; acc.y += v0.y; acc.z += v0.z; acc.w += v0.w;
    }
    float iv = 1.0f / (float)max(end - beg, 1);
    acc.x *= iv; acc.y *= iv; acc.z *= iv; acc.w *= iv;
    *(float4*)(agg + (size_t)node * 128 + lane4) = acc;
}

// ================= split-bf16 MFMA GEMM — LDS-free K-loop =================
// C = A @ W^T, A/W f32 emulated as hi+lo bf16: C ~= Ah*Wh + Al*Wh + Ah*Wl.
// Both operand fragments are CONTIGUOUS in memory (A-frag = 8 f32 at
// A[row][quad*8], W-frag = 8 bf16 at W[col][quad*8]), so they're loaded
// directly global->registers. NO __shared__ tiles, NO barriers in the K-loop:
// the old version spent ~312 LDS-pipe cyc/iter (staging hi+lo) vs 230 MFMA
// cyc/iter -> MfmaUtil capped at ~20% across R5-R7. W reuse is served by
// L1/L2 (32 KB W-slice per iter, L1-resident; A frags shared by 4 waves).
// Wave owns 64 rows x 64 cols: block = 64 rows x 256 cols, 4 waves.

__device__ __forceinline__ void splitv(float4 v0, float4 v1,
                                       bf16x8& h, bf16x8& l) {
    float f[8] = {v0.x, v0.y, v0.z, v0.w, v1.x, v1.y, v1.z, v1.w};
    #pragma unroll
    for (int i = 0; i < 8; i++) {
        bf16_t hi = (bf16_t)f[i];
        h[i] = hi;
        l[i] = (bf16_t)(f[i] - (float)hi);
    }
}

// Layer-1 GEMM, A = [agg | x] (each M x 128); fused epilogue h1 = relu(l2norm(C+b1))
__global__ __launch_bounds__(256) void k_gemm_l1(const float* __restrict__ Aa,
        const float* __restrict__ Ax, const bf16_t* __restrict__ Wh,
        const bf16_t* __restrict__ Wl, const float* __restrict__ bias,
        float* __restrict__ H) {
    __shared__ float pr[64][4];
    int t = threadIdx.x;
    int wave = t >> 6, lane = t & 63, quad = lane >> 4, l16 = lane & 15;
    int r0 = blockIdx.x * 64;
    f32x4 acc[4][4] = {};
    // per-mt clamped A row offsets (rows r0+mt*16+l16)
    size_t aoff[4];
    #pragma unroll
    for (int mt = 0; mt < 4; mt++) {
        int row = r0 + mt * 16 + l16;
        if (row >= NN) row = NN - 1;
        aoff[mt] = (size_t)row * 128;
    }
    // per-nt W row offsets (cols wave*64+nt*16+l16)
    size_t woff[4];
    #pragma unroll
    for (int nt = 0; nt < 4; nt++)
        woff[nt] = (size_t)(wave * 64 + nt * 16 + l16) * 256;
    int kq = quad * 8;
    for (int it = 0; it < 8; it++) {
        int k0 = it * 32;
        const float* Asrc = (k0 < 128) ? Aa : Ax;
        int kb = ((k0 < 128) ? k0 : (k0 - 128)) + kq;
        bf16x8 ah[4], al[4], bh[4], bl[4];
        #pragma unroll
        for (int mt = 0; mt < 4; mt++) {
            const float* p = Asrc + aoff[mt] + kb;
            splitv(*(const float4*)p, *(const float4*)(p + 4), ah[mt], al[mt]);
        }
        #pragma unroll
        for (int nt = 0; nt < 4; nt++) {
            bh[nt] = *(const bf16x8*)&Wh[woff[nt] + k0 + kq];
            bl[nt] = *(const bf16x8*)&Wl[woff[nt] + k0 + kq];
        }
        #pragma unroll
        for (int mt = 0; mt < 4; mt++)
            #pragma unroll
            for (int nt = 0; nt < 4; nt++) {
                acc[mt][nt] = __builtin_amdgcn_mfma_f32_16x16x32_bf16(ah[mt], bh[nt], acc[mt][nt], 0, 0, 0);
                acc[mt][nt] = __builtin_amdgcn_mfma_f32_16x16x32_bf16(al[mt], bh[nt], acc[mt][nt], 0, 0, 0);
                acc[mt][nt] = __builtin_amdgcn_mfma_f32_16x16x32_bf16(ah[mt], bl[nt], acc[mt][nt], 0, 0, 0);
            }
    }
    // ---- fused epilogue: bias, row L2-norm across 256 cols, relu ----
    float bcol[4];
    #pragma unroll
    for (int nt = 0; nt < 4; nt++) bcol[nt] = bias[wave * 64 + nt * 16 + l16];
    #pragma unroll
    for (int mt = 0; mt < 4; mt++)
        #pragma unroll
        for (int nt = 0; nt < 4; nt++)
            #pragma unroll
            for (int rg = 0; rg < 4; rg++)
                acc[mt][nt][rg] += bcol[nt];
    float ss[4][4];
    #pragma unroll
    for (int mt = 0; mt < 4; mt++)
        #pragma unroll
        for (int rg = 0; rg < 4; rg++) {
            float s = 0.f;
            #pragma unroll
            for (int nt = 0; nt < 4; nt++) s += acc[mt][nt][rg] * acc[mt][nt][rg];
            #pragma unroll
            for (int off = 1; off < 16; off <<= 1) s += __shfl_xor(s, off, 64);
            ss[mt][rg] = s;
        }
    if (l16 == 0) {
        #pragma unroll
        for (int mt = 0; mt < 4; mt++)
            #pragma unroll
            for (int rg = 0; rg < 4; rg++)
                pr[mt * 16 + quad * 4 + rg][wave] = ss[mt][rg];
    }
    __syncthreads();
    #pragma unroll
    for (int mt = 0; mt < 4; mt++)
        #pragma unroll
        for (int rg = 0; rg < 4; rg++) {
            int lr = mt * 16 + quad * 4 + rg;
            int row = r0 + lr;
            if (row >= NN) continue;
            float tot = pr[lr][0] + pr[lr][1] + pr[lr][2] + pr[lr][3];
            float inv = 1.0f / fmaxf(sqrtf(tot), 1e-12f);
            #pragma unroll
            for (int nt = 0; nt < 4; nt++) {
                int col = wave * 64 + nt * 16 + l16;
                H[(size_t)row * 256 + col] = fmaxf(acc[mt][nt][rg] * inv, 0.f);
            }
        }
}

// Layer-2 GEMM: C2 = h1 @ [W2l;W2r]^T, plain f32 store (LDS-free)
__global__ __launch_bounds__(256) void k_gemm_l2(const float* __restrict__ A,
        const bf16_t* __restrict__ Wh, const bf16_t* __restrict__ Wl,
        float* __restrict__ C) {
    int t = threadIdx.x;
    int wave = t >> 6, lane = t & 63, quad = lane >> 4, l16 = lane & 15;
    int r0 = blockIdx.x * 64;
    f32x4 acc[4][4] = {};
    size_t aoff[4];
    #pragma unroll
    for (int mt = 0; mt < 4; mt++) {
        int row = r0 + mt * 16 + l16;
        if (row >= NN) row = NN - 1;
        aoff[mt] = (size_t)row * 256;
    }
    size_t woff[4];
    #pragma unroll
    for (int nt = 0; nt < 4; nt++)
        woff[nt] = (size_t)(wave * 64 + nt * 16 + l16) * 256;
    int kq = quad * 8;
    for (int it = 0; it < 8; it++) {
        int k0 = it * 32;
        bf16x8 ah[4], al[4], bh[4], bl[4];
        #pragma unroll
        for (int mt = 0; mt < 4; mt++) {
            const float* p = A + aoff[mt] + k0 + kq;
            splitv(*(const float4*)p, *(const float4*)(p + 4), ah[mt], al[mt]);
        }
        #pragma unroll
        for (int nt = 0; nt < 4; nt++) {
            bh[nt] = *(const bf16x8*)&Wh[woff[nt] + k0 + kq];
            bl[nt] = *(const bf16x8*)&Wl[woff[nt] + k0 + kq];
        }
        #pragma unroll
        for (int mt = 0; mt < 4; mt++)
            #pragma unroll
            for (int nt = 0; nt < 4; nt++) {
                acc[mt][nt] = __builtin_amdgcn_mfma_f32_16x16x32_bf16(ah[mt], bh[nt], acc[mt][nt], 0, 0, 0);
                acc[mt][nt] = __builtin_amdgcn_mfma_f32_16x16x32_bf16(al[mt], bh[nt], acc[mt][nt], 0, 0, 0);
                acc[mt][nt] = __builtin_amdgcn_mfma_f32_16x16x32_bf16(ah[mt], bl[nt], acc[mt][nt], 0, 0, 0);
            }
    }
    #pragma unroll
    for (int mt = 0; mt < 4; mt++)
        #pragma unroll
        for (int rg = 0; rg < 4; rg++) {
            int row = r0 + mt * 16 + quad * 4 + rg;
            if (row >= NN) continue;
            #pragma unroll
            for (int nt = 0; nt < 4; nt++) {
                int col = wave * 64 + nt * 16 + l16;
                C[(size_t)row * 256 + col] = acc[mt][nt][rg];
            }
        }
}

// ==== fused layer-2 tail: gather-mean p2 + combine + norm + q3 ====

__global__ __launch_bounds__(256) void k_gather_combine(const float* __restrict__ C2,
        const int* __restrict__ rowptr, const int* __restrict__ csr,
        const float* __restrict__ b2, const float* __restrict__ W3l,
        float* __restrict__ h2, float* __restrict__ q3) {
    __shared__ float sw[256];
    int t = threadIdx.x;
    sw[t] = W3l[t];
    __syncthreads();
    int tid = blockIdx.x * 256 + t;
    int node = tid >> 5;
    if (node >= NN) return;
    int l = tid & 31;
    int lane4 = l << 2;
    int beg = rowptr[node], end = rowptr[node + 1];
    float4 acc = make_float4(0.f, 0.f, 0.f, 0.f);
    int e = beg;
    for (; e + 1 < end; e += 2) {
        int s0 = csr[e], s1 = csr[e + 1];
        float4 v0 = *(const float4*)(C2 + (size_t)s0 * 256 + lane4);
        float4 v1 = *(const float4*)(C2 + (size_t)s1 * 256 + lane4);
        acc.x += v0.x + v1.x; acc.y += v0.y + v1.y;
        acc.z += v0.z + v1.z; acc.w += v0.w + v1.w;
    }
    if (e < end) {
        int s0 = csr[e];
        float4 v0 = *(const float4*)(C2 + (size_t)s0 * 256 + lane4);
        acc.x += v0.x; acc.y += v0.y; acc.z += v0.z; acc.w += v0.w;
    }
    float iv = 1.0f / (float)max(end - beg, 1);
    float4 r = *(const float4*)&C2[(size_t)node * 256 + 128 + lane4];
    float4 b = *(const float4*)&b2[lane4];
    float v0 = acc.x * iv + r.x + b.x;
    float v1 = acc.y * iv + r.y + b.y;
    float v2 = acc.z * iv + r.z + b.z;
    float v3 = acc.w * iv + r.w + b.w;
    float s = v0 * v0 + v1 * v1 + v2 * v2 + v3 * v3;
    #pragma unroll
    for (int off = 16; off > 0; off >>= 1) s += __shfl_xor(s, off, 64);
    float invn = 1.0f / fmaxf(sqrtf(s), 1e-12f);
    float4 o;
    o.x = fmaxf(v0 * invn, 0.f); o.y = fmaxf(v1 * invn, 0.f);
    o.z = fmaxf(v2 * invn, 0.f); o.w = fmaxf(v3 * invn, 0.f);
    *(float4*)&h2[(size_t)node * 128 + lane4] = o;
    float a0 = o.x * sw[lane4] + o.y * sw[lane4+1] + o.z * sw[lane4+2] + o.w * sw[lane4+3];
    float a1 = o.x * sw[128+lane4] + o.y * sw[129+lane4] + o.z * sw[130+lane4] + o.w * sw[131+lane4];
    #pragma unroll
    for (int off = 16; off > 0; off >>= 1) {
        a0 += __shfl_xor(a0, off, 64);
        a1 += __shfl_xor(a1, off, 64);
    }
    if (l == 0) {
        q3[2 * node] = a0;
        q3[2 * node + 1] = a1;
    }
}

// ================= final (absorbs the 2-wide q3 gather) =================

__global__ __launch_bounds__(256) void k_final(const float* __restrict__ h2,
        const float* __restrict__ W3r, const float* __restrict__ b3,
        const float* __restrict__ q3, const int* __restrict__ rowptr,
        const int* __restrict__ csr, float* __restrict__ out) {
    __shared__ float sw[256];
    int t = threadIdx.x;
    sw[t] = W3r[t];
    __syncthreads();
    int i = blockIdx.x * 256 + t;
    if (i >= NN) return;
    int beg = rowptr[i], end = rowptr[i + 1];
    float g0 = 0.f, g1 = 0.f;
    for (int e = beg; e < end; e++) {
        int s = csr[e];
        g0 += q3[2 * s];
        g1 += q3[2 * s + 1];
    }
    float ivd = 1.0f / (float)max(end - beg, 1);
    g0 *= ivd; g1 *= ivd;
    const float4* row = (const float4*)(h2 + (size_t)i * 128);
    float a0 = 0.f, a1 = 0.f;
    #pragma unroll
    for (int q = 0; q < 32; q++) {
        float4 v = row[q];
        a0 += v.x * sw[4*q] + v.y * sw[4*q+1] + v.z * sw[4*q+2] + v.w * sw[4*q+3];
        a1 += v.x * sw[128+4*q] + v.y * sw[129+4*q] + v.z * sw[130+4*q] + v.w * sw[131+4*q];
    }
    float v0 = g0 + a0 + b3[0];
    float v1 = g1 + a1 + b3[1];
    float invn = 1.0f / fmaxf(sqrtf(v0 * v0 + v1 * v1), 1e-12f);
    v0 *= invn; v1 *= invn;
    float mx = fmaxf(v0, v1);
    float l = logf(expf(v0 - mx) + expf(v1 - mx));
    out[2 * i] = v0 - mx - l;
    out[2 * i + 1] = v1 - mx - l;
}

// ================= launch =================

extern "C" void kernel_launch(void* const* d_in, const int* in_sizes, int n_in,
                              void* d_out, int out_size, void* d_ws, size_t ws_size,
                              hipStream_t stream) {
    const float* x   = (const float*)d_in[0];
    const int*   ei  = (const int*)d_in[1];
    const float* W1l = (const float*)d_in[2];
    const float* W1r = (const float*)d_in[3];
    const float* b1  = (const float*)d_in[4];
    const float* W2l = (const float*)d_in[5];
    const float* W2r = (const float*)d_in[6];
    const float* b2  = (const float*)d_in[7];
    const float* W3l = (const float*)d_in[8];
    const float* W3r = (const float*)d_in[9];
    const float* b3  = (const float*)d_in[10];
    float* out = (float*)d_out;
    const int* src = ei;
    const int* dst = ei + NE;

    // ---- workspace layout ----
    int* deg    = (int*)d_ws;                     // 102400
    int* rowptr = deg + 102400;
    int* cursor = rowptr + 102400;
    int* csr    = cursor + 102400;                // 655360
    int* bsum   = csr + 655360;                   // 128
    int* boff   = bsum + 128;                     // 128
    bf16_t* W1h  = (bf16_t*)(boff + 128);         // 65536 bf16 each
    bf16_t* W1lo = W1h + 65536;
    bf16_t* W2h  = W1lo + 65536;
    bf16_t* W2lo = W2h + 65536;
    float* aggA = (float*)(W2lo + 65536);         // 12.8M f32 (layer-1 agg)
    float* h1   = aggA + 12800000;                // MPAD*256 f32 (reused as h2)
    float* C2   = h1 + (size_t)MPAD * 256;        // MPAD*256 f32
    float* q3   = C2 + (size_t)MPAD * 256;        // 200000
    float* h2   = h1;                             // reuse after L2 GEMM consumed h1

    // ---- CSR build (multi-block scan) ----
    hipMemsetAsync(deg, 0, NN * sizeof(int), stream);
    k_hist<<<(NE + 255) / 256, 256, 0, stream>>>(dst, deg);
    k_bsum<<<NBLK, 1024, 0, stream>>>(deg, bsum);
    k_bscan<<<1, 64, 0, stream>>>(bsum, boff, rowptr);
    k_scan2<<<NBLK, 1024, 0, stream>>>(deg, boff, rowptr, cursor);
    k_fill<<<(NE + 255) / 256, 256, 0, stream>>>(src, dst, cursor, csr);

    // ---- weight split ----
    k_split_w1<<<256, 256, 0, stream>>>(W1l, W1r, W1h, W1lo);
    k_split_w2<<<256, 256, 0, stream>>>(W2l, W2r, W2h, W2lo);

    // ---- layer 1 ----
    k_gather128s<<<(NN * 32 + 255) / 256, 256, 0, stream>>>(x, rowptr, csr, aggA);
    k_gemm_l1<<<MPAD / 64, 256, 0, stream>>>(aggA, x, W1h, W1lo, b1, h1);

    // ---- layer 2 (gather+combine+q3 fused) ----
    k_gemm_l2<<<MPAD / 64, 256, 0, stream>>>(h1, W2h, W2lo, C2);
    k_gather_combine<<<(NN * 32 + 255) / 256, 256, 0, stream>>>(C2, rowptr, csr, b2, W3l, h2, q3);

    // ---- layer 3 ----
    k_final<<<(NN + 255) / 256, 256, 0, stream>>>(h2, W3r, b3, q3, rowptr, csr, out);
}

// Round 9
// 457.675 us; speedup vs baseline: 1.1541x; 1.1541x over previous
//
#include <hip/hip_runtime.h>
#include <math.h>

#define NN 100000
#define NE 640000
#define MPAD2 100096  // NN rounded up to 128
#define NBLK 98       // ceil(NN / 1024)

typedef __bf16 bf16_t;
typedef bf16_t bf16x8 __attribute__((ext_vector_type(8)));
typedef float  f32x4  __attribute__((ext_vector_type(4)));

// ================= CSR build =================

__global__ __launch_bounds__(256) void k_hist(const int* __restrict__ dst,
                                              int* __restrict__ deg) {
    int e = blockIdx.x * 256 + threadIdx.x;
    if (e < NE) atomicAdd(&deg[dst[e]], 1);
}

__global__ __launch_bounds__(1024) void k_bsum(const int* __restrict__ deg,
                                               int* __restrict__ bsum) {
    __shared__ int warr[16];
    int t = threadIdx.x;
    int i = blockIdx.x * 1024 + t;
    int v = (i < NN) ? deg[i] : 0;
    int lane = t & 63, wid = t >> 6;
    #pragma unroll
    for (int off = 32; off > 0; off >>= 1) v += __shfl_xor(v, off, 64);
    if (lane == 0) warr[wid] = v;
    __syncthreads();
    if (t < 16) {
        int s = warr[t];
        #pragma unroll
        for (int off = 8; off > 0; off >>= 1) s += __shfl_xor(s, off, 64);
        if (t == 0) bsum[blockIdx.x] = s;
    }
}

__global__ __launch_bounds__(64) void k_bscan(const int* __restrict__ bsum,
        int* __restrict__ boff, int* __restrict__ rowptr) {
    int lane = threadIdx.x;
    int carry = 0;
    for (int base = 0; base < NBLK; base += 64) {
        int i = base + lane;
        int v = (i < NBLK) ? bsum[i] : 0;
        int s = v;
        #pragma unroll
        for (int off = 1; off < 64; off <<= 1) {
            int u = __shfl_up(s, off, 64);
            if (lane >= off) s += u;
        }
        if (i < NBLK) boff[i] = carry + s - v;
        carry += __shfl(s, 63, 64);
    }
    if (lane == 0) rowptr[NN] = NE;
}

__global__ __launch_bounds__(1024) void k_scan2(const int* __restrict__ deg,
        const int* __restrict__ boff, int* __restrict__ rowptr,
        int* __restrict__ cursor) {
    __shared__ int wsum[16];
    __shared__ int woff[16];
    int t = threadIdx.x;
    int lane = t & 63, wid = t >> 6;
    int i = blockIdx.x * 1024 + t;
    int v = (i < NN) ? deg[i] : 0;
    int s = v;
    #pragma unroll
    for (int off = 1; off < 64; off <<= 1) {
        int u = __shfl_up(s, off, 64);
        if (lane >= off) s += u;
    }
    if (lane == 63) wsum[wid] = s;
    __syncthreads();
    if (wid == 0) {
        int ws = (lane < 16) ? wsum[lane] : 0;
        #pragma unroll
        for (int off = 1; off < 16; off <<= 1) {
            int u = __shfl_up(ws, off, 64);
            if (lane >= off) ws += u;
        }
        if (lane < 16) woff[lane] = ws;
    }
    __syncthreads();
    if (i < NN) {
        int excl = boff[blockIdx.x] + (s - v) + (wid ? woff[wid - 1] : 0);
        rowptr[i] = excl;
        cursor[i] = excl;
    }
}

__global__ __launch_bounds__(256) void k_fill(const int* __restrict__ src,
        const int* __restrict__ dst, int* __restrict__ cursor,
        int* __restrict__ csr) {
    int e = blockIdx.x * 256 + threadIdx.x;
    if (e >= NE) return;
    int p = atomicAdd(&cursor[dst[e]], 1);
    csr[p] = src[e];
}

// ================= weight split (f32 -> hi/lo bf16) =================

__global__ __launch_bounds__(256) void k_split_w1(const float* __restrict__ W1l,
        const float* __restrict__ W1r, bf16_t* __restrict__ Wh,
        bf16_t* __restrict__ Wl) {
    int j = blockIdx.x, t = threadIdx.x;
    float f = (t < 128) ? W1l[j * 128 + t] : W1r[j * 128 + (t - 128)];
    bf16_t h = (bf16_t)f;
    bf16_t l = (bf16_t)(f - (float)h);
    Wh[j * 256 + t] = h;
    Wl[j * 256 + t] = l;
}

__global__ __launch_bounds__(256) void k_split_w2(const float* __restrict__ W2l,
        const float* __restrict__ W2r, bf16_t* __restrict__ Wh,
        bf16_t* __restrict__ Wl) {
    int j = blockIdx.x, t = threadIdx.x;
    float f = (j < 128) ? W2l[j * 256 + t] : W2r[(j - 128) * 256 + t];
    bf16_t h = (bf16_t)f;
    bf16_t l = (bf16_t)(f - (float)h);
    Wh[j * 256 + t] = h;
    Wl[j * 256 + t] = l;
}

// ================= gather-mean for layer 1 (f32, 128 wide) =================

__global__ __launch_bounds__(256) void k_gather128s(const float* __restrict__ feat,
        const int* __restrict__ rowptr, const int* __restrict__ csr,
        float* __restrict__ agg) {
    int tid = blockIdx.x * 256 + threadIdx.x;
    int node = tid >> 5;
    if (node >= NN) return;
    int lane4 = (tid & 31) << 2;
    int beg = rowptr[node], end = rowptr[node + 1];
    float4 acc = make_float4(0.f, 0.f, 0.f, 0.f);
    int e = beg;
    for (; e + 1 < end; e += 2) {
        int s0 = csr[e], s1 = csr[e + 1];
        float4 v0 = *(const float4*)(feat + (size_t)s0 * 128 + lane4);
        float4 v1 = *(const float4*)(feat + (size_t)s1 * 128 + lane4);
        acc.x += v0.x + v1.x; acc.y += v0.y + v1.y;
        acc.z += v0.z + v1.z; acc.w += v0.w + v1.w;
    }
    if (e < end) {
        int s0 = csr[e];
        float4 v0 = *(const float4*)(feat + (size_t)s0 * 128 + lane4);
        acc.x += v0.x; acc.y += v0.y; acc.z += v0.z; acc.w += v0.w;
    }
    float iv = 1.0f / (float)max(end - beg, 1);
    acc.x *= iv; acc.y *= iv; acc.z *= iv; acc.w *= iv;
    *(float4*)(agg + (size_t)node * 128 + lane4) = acc;
}

// ================= split-bf16 MFMA GEMM, BM=128 =================
// C = A @ W^T, A/W f32 emulated as hi+lo bf16: C ~= Ah*Wh + Al*Wh + Ah*Wl.
// block 256 = 4 waves; BM=128 (wave tile 8mt x 4nt = 128x64), BN=256, BK=32.
// Per wave-iter: MFMA 96 x ~4.85 = 466 cyc vs LDS 36 x ~12 = 432 cyc ->
// MFMA-dominant (BM=64 was 233:312, LDS-bound, util stuck ~17-20% R5-R7;
// LDS-free R8 was L1-divergence-bound, 12%). Stride 34 bf16 = 17 dwords
// (odd): all b128 LDS ops <=2-way bank aliasing (free, m136).

#define PADK 2

__device__ __forceinline__ void splitv(float4 v0, float4 v1,
                                       bf16x8& h, bf16x8& l) {
    float f[8] = {v0.x, v0.y, v0.z, v0.w, v1.x, v1.y, v1.z, v1.w};
    #pragma unroll
    for (int i = 0; i < 8; i++) {
        bf16_t hi = (bf16_t)f[i];
        h[i] = hi;
        l[i] = (bf16_t)(f[i] - (float)hi);
    }
}

// Layer-1 GEMM, A = [agg | x] (each M x 128); fused epilogue h1 = relu(l2norm(C+b1))
__global__ __launch_bounds__(256, 2) void k_gemm_l1(const float* __restrict__ Aa,
        const float* __restrict__ Ax, const bf16_t* __restrict__ Wh,
        const bf16_t* __restrict__ Wl, const float* __restrict__ bias,
        float* __restrict__ H) {
    __shared__ bf16_t sAh[128][32 + PADK], sAl[128][32 + PADK];
    __shared__ bf16_t sWh[256][32 + PADK], sWl[256][32 + PADK];
    __shared__ float pr[128][4];
    int t = threadIdx.x;
    int wave = t >> 6, lane = t & 63, quad = lane >> 4, l16 = lane & 15;
    int r0 = blockIdx.x * 128;
    f32x4 acc[8][4] = {};
    int arow = t >> 1, ahalf = (t & 1) * 16;   // A staging: row, 16-f32 half
    int grow = r0 + arow; if (grow >= NN) grow = NN - 1;
    for (int it = 0; it < 8; it++) {
        int k0 = it * 32;
        const float* Asrc = (k0 < 128) ? Aa : Ax;
        int kb = (k0 < 128) ? k0 : (k0 - 128);
        __syncthreads();   // prev iter's frag readers done
        {
            const float* p = &Asrc[(size_t)grow * 128 + kb + ahalf];
            bf16x8 h0, l0, h1, l1;
            splitv(*(const float4*)p, *(const float4*)(p + 4), h0, l0);
            splitv(*(const float4*)(p + 8), *(const float4*)(p + 12), h1, l1);
            *(bf16x8*)&sAh[arow][ahalf] = h0;
            *(bf16x8*)&sAh[arow][ahalf + 8] = h1;
            *(bf16x8*)&sAl[arow][ahalf] = l0;
            *(bf16x8*)&sAl[arow][ahalf + 8] = l1;
            const bf16_t* wp = &Wh[(size_t)t * 256 + k0];
            const bf16_t* lp = &Wl[(size_t)t * 256 + k0];
            #pragma unroll
            for (int s = 0; s < 4; s++) {
                *(bf16x8*)&sWh[t][s * 8] = *(const bf16x8*)(wp + s * 8);
                *(bf16x8*)&sWl[t][s * 8] = *(const bf16x8*)(lp + s * 8);
            }
        }
        __syncthreads();
        bf16x8 bh[4], bl[4];
        #pragma unroll
        for (int nt = 0; nt < 4; nt++) {
            bh[nt] = *(bf16x8*)&sWh[wave * 64 + nt * 16 + l16][quad * 8];
            bl[nt] = *(bf16x8*)&sWl[wave * 64 + nt * 16 + l16][quad * 8];
        }
        #pragma unroll
        for (int mt = 0; mt < 8; mt++) {
            bf16x8 ah = *(bf16x8*)&sAh[mt * 16 + l16][quad * 8];
            bf16x8 al = *(bf16x8*)&sAl[mt * 16 + l16][quad * 8];
            #pragma unroll
            for (int nt = 0; nt < 4; nt++) {
                acc[mt][nt] = __builtin_amdgcn_mfma_f32_16x16x32_bf16(ah, bh[nt], acc[mt][nt], 0, 0, 0);
                acc[mt][nt] = __builtin_amdgcn_mfma_f32_16x16x32_bf16(al, bh[nt], acc[mt][nt], 0, 0, 0);
                acc[mt][nt] = __builtin_amdgcn_mfma_f32_16x16x32_bf16(ah, bl[nt], acc[mt][nt], 0, 0, 0);
            }
        }
    }
    // ---- fused epilogue: bias, row L2-norm across 256 cols, relu ----
    float bcol[4];
    #pragma unroll
    for (int nt = 0; nt < 4; nt++) bcol[nt] = bias[wave * 64 + nt * 16 + l16];
    #pragma unroll
    for (int mt = 0; mt < 8; mt++)
        #pragma unroll
        for (int nt = 0; nt < 4; nt++)
            #pragma unroll
            for (int rg = 0; rg < 4; rg++)
                acc[mt][nt][rg] += bcol[nt];
    float ss[8][4];
    #pragma unroll
    for (int mt = 0; mt < 8; mt++)
        #pragma unroll
        for (int rg = 0; rg < 4; rg++) {
            float s = 0.f;
            #pragma unroll
            for (int nt = 0; nt < 4; nt++) s += acc[mt][nt][rg] * acc[mt][nt][rg];
            #pragma unroll
            for (int off = 1; off < 16; off <<= 1) s += __shfl_xor(s, off, 64);
            ss[mt][rg] = s;
        }
    if (l16 == 0) {
        #pragma unroll
        for (int mt = 0; mt < 8; mt++)
            #pragma unroll
            for (int rg = 0; rg < 4; rg++)
                pr[mt * 16 + quad * 4 + rg][wave] = ss[mt][rg];
    }
    __syncthreads();
    #pragma unroll
    for (int mt = 0; mt < 8; mt++)
        #pragma unroll
        for (int rg = 0; rg < 4; rg++) {
            int lr = mt * 16 + quad * 4 + rg;
            int row = r0 + lr;
            if (row >= NN) continue;
            float tot = pr[lr][0] + pr[lr][1] + pr[lr][2] + pr[lr][3];
            float inv = 1.0f / fmaxf(sqrtf(tot), 1e-12f);
            #pragma unroll
            for (int nt = 0; nt < 4; nt++) {
                int col = wave * 64 + nt * 16 + l16;
                H[(size_t)row * 256 + col] = fmaxf(acc[mt][nt][rg] * inv, 0.f);
            }
        }
}

// Layer-2 GEMM: C2 = h1 @ [W2l;W2r]^T, plain f32 store, BM=128
__global__ __launch_bounds__(256, 2) void k_gemm_l2(const float* __restrict__ A,
        const bf16_t* __restrict__ Wh, const bf16_t* __restrict__ Wl,
        float* __restrict__ C) {
    __shared__ bf16_t sAh[128][32 + PADK], sAl[128][32 + PADK];
    __shared__ bf16_t sWh[256][32 + PADK], sWl[256][32 + PADK];
    int t = threadIdx.x;
    int wave = t >> 6, lane = t & 63, quad = lane >> 4, l16 = lane & 15;
    int r0 = blockIdx.x * 128;
    f32x4 acc[8][4] = {};
    int arow = t >> 1, ahalf = (t & 1) * 16;
    int grow = r0 + arow; if (grow >= NN) grow = NN - 1;
    for (int it = 0; it < 8; it++) {
        int k0 = it * 32;
        __syncthreads();
        {
            const float* p = &A[(size_t)grow * 256 + k0 + ahalf];
            bf16x8 h0, l0, h1, l1;
            splitv(*(const float4*)p, *(const float4*)(p + 4), h0, l0);
            splitv(*(const float4*)(p + 8), *(const float4*)(p + 12), h1, l1);
            *(bf16x8*)&sAh[arow][ahalf] = h0;
            *(bf16x8*)&sAh[arow][ahalf + 8] = h1;
            *(bf16x8*)&sAl[arow][ahalf] = l0;
            *(bf16x8*)&sAl[arow][ahalf + 8] = l1;
            const bf16_t* wp = &Wh[(size_t)t * 256 + k0];
            const bf16_t* lp = &Wl[(size_t)t * 256 + k0];
            #pragma unroll
            for (int s = 0; s < 4; s++) {
                *(bf16x8*)&sWh[t][s * 8] = *(const bf16x8*)(wp + s * 8);
                *(bf16x8*)&sWl[t][s * 8] = *(const bf16x8*)(lp + s * 8);
            }
        }
        __syncthreads();
        bf16x8 bh[4], bl[4];
        #pragma unroll
        for (int nt = 0; nt < 4; nt++) {
            bh[nt] = *(bf16x8*)&sWh[wave * 64 + nt * 16 + l16][quad * 8];
            bl[nt] = *(bf16x8*)&sWl[wave * 64 + nt * 16 + l16][quad * 8];
        }
        #pragma unroll
        for (int mt = 0; mt < 8; mt++) {
            bf16x8 ah = *(bf16x8*)&sAh[mt * 16 + l16][quad * 8];
            bf16x8 al = *(bf16x8*)&sAl[mt * 16 + l16][quad * 8];
            #pragma unroll
            for (int nt = 0; nt < 4; nt++) {
                acc[mt][nt] = __builtin_amdgcn_mfma_f32_16x16x32_bf16(ah, bh[nt], acc[mt][nt], 0, 0, 0);
                acc[mt][nt] = __builtin_amdgcn_mfma_f32_16x16x32_bf16(al, bh[nt], acc[mt][nt], 0, 0, 0);
                acc[mt][nt] = __builtin_amdgcn_mfma_f32_16x16x32_bf16(ah, bl[nt], acc[mt][nt], 0, 0, 0);
            }
        }
    }
    #pragma unroll
    for (int mt = 0; mt < 8; mt++)
        #pragma unroll
        for (int rg = 0; rg < 4; rg++) {
            int row = r0 + mt * 16 + quad * 4 + rg;
            if (row >= NN) continue;
            #pragma unroll
            for (int nt = 0; nt < 4; nt++) {
                int col = wave * 64 + nt * 16 + l16;
                C[(size_t)row * 256 + col] = acc[mt][nt][rg];
            }
        }
}

// ==== fused layer-2 tail: gather-mean p2 + combine + norm + q3 ====

__global__ __launch_bounds__(256) void k_gather_combine(const float* __restrict__ C2,
        const int* __restrict__ rowptr, const int* __restrict__ csr,
        const float* __restrict__ b2, const float* __restrict__ W3l,
        float* __restrict__ h2, float* __restrict__ q3) {
    __shared__ float sw[256];
    int t = threadIdx.x;
    sw[t] = W3l[t];
    __syncthreads();
    int tid = blockIdx.x * 256 + t;
    int node = tid >> 5;
    if (node >= NN) return;
    int l = tid & 31;
    int lane4 = l << 2;
    int beg = rowptr[node], end = rowptr[node + 1];
    float4 acc = make_float4(0.f, 0.f, 0.f, 0.f);
    int e = beg;
    for (; e + 1 < end; e += 2) {
        int s0 = csr[e], s1 = csr[e + 1];
        float4 v0 = *(const float4*)(C2 + (size_t)s0 * 256 + lane4);
        float4 v1 = *(const float4*)(C2 + (size_t)s1 * 256 + lane4);
        acc.x += v0.x + v1.x; acc.y += v0.y + v1.y;
        acc.z += v0.z + v1.z; acc.w += v0.w + v1.w;
    }
    if (e < end) {
        int s0 = csr[e];
        float4 v0 = *(const float4*)(C2 + (size_t)s0 * 256 + lane4);
        acc.x += v0.x; acc.y += v0.y; acc.z += v0.z; acc.w += v0.w;
    }
    float iv = 1.0f / (float)max(end - beg, 1);
    float4 r = *(const float4*)&C2[(size_t)node * 256 + 128 + lane4];
    float4 b = *(const float4*)&b2[lane4];
    float v0 = acc.x * iv + r.x + b.x;
    float v1 = acc.y * iv + r.y + b.y;
    float v2 = acc.z * iv + r.z + b.z;
    float v3 = acc.w * iv + r.w + b.w;
    float s = v0 * v0 + v1 * v1 + v2 * v2 + v3 * v3;
    #pragma unroll
    for (int off = 16; off > 0; off >>= 1) s += __shfl_xor(s, off, 64);
    float invn = 1.0f / fmaxf(sqrtf(s), 1e-12f);
    float4 o;
    o.x = fmaxf(v0 * invn, 0.f); o.y = fmaxf(v1 * invn, 0.f);
    o.z = fmaxf(v2 * invn, 0.f); o.w = fmaxf(v3 * invn, 0.f);
    *(float4*)&h2[(size_t)node * 128 + lane4] = o;
    float a0 = o.x * sw[lane4] + o.y * sw[lane4+1] + o.z * sw[lane4+2] + o.w * sw[lane4+3];
    float a1 = o.x * sw[128+lane4] + o.y * sw[129+lane4] + o.z * sw[130+lane4] + o.w * sw[131+lane4];
    #pragma unroll
    for (int off = 16; off > 0; off >>= 1) {
        a0 += __shfl_xor(a0, off, 64);
        a1 += __shfl_xor(a1, off, 64);
    }
    if (l == 0) {
        q3[2 * node] = a0;
        q3[2 * node + 1] = a1;
    }
}

// ================= final (absorbs the 2-wide q3 gather) =================

__global__ __launch_bounds__(256) void k_final(const float* __restrict__ h2,
        const float* __restrict__ W3r, const float* __restrict__ b3,
        const float* __restrict__ q3, const int* __restrict__ rowptr,
        const int* __restrict__ csr, float* __restrict__ out) {
    __shared__ float sw[256];
    int t = threadIdx.x;
    sw[t] = W3r[t];
    __syncthreads();
    int i = blockIdx.x * 256 + t;
    if (i >= NN) return;
    int beg = rowptr[i], end = rowptr[i + 1];
    float g0 = 0.f, g1 = 0.f;
    for (int e = beg; e < end; e++) {
        int s = csr[e];
        g0 += q3[2 * s];
        g1 += q3[2 * s + 1];
    }
    float ivd = 1.0f / (float)max(end - beg, 1);
    g0 *= ivd; g1 *= ivd;
    const float4* row = (const float4*)(h2 + (size_t)i * 128);
    float a0 = 0.f, a1 = 0.f;
    #pragma unroll
    for (int q = 0; q < 32; q++) {
        float4 v = row[q];
        a0 += v.x * sw[4*q] + v.y * sw[4*q+1] + v.z * sw[4*q+2] + v.w * sw[4*q+3];
        a1 += v.x * sw[128+4*q] + v.y * sw[129+4*q] + v.z * sw[130+4*q] + v.w * sw[131+4*q];
    }
    float v0 = g0 + a0 + b3[0];
    float v1 = g1 + a1 + b3[1];
    float invn = 1.0f / fmaxf(sqrtf(v0 * v0 + v1 * v1), 1e-12f);
    v0 *= invn; v1 *= invn;
    float mx = fmaxf(v0, v1);
    float l = logf(expf(v0 - mx) + expf(v1 - mx));
    out[2 * i] = v0 - mx - l;
    out[2 * i + 1] = v1 - mx - l;
}

// ================= launch =================

extern "C" void kernel_launch(void* const* d_in, const int* in_sizes, int n_in,
                              void* d_out, int out_size, void* d_ws, size_t ws_size,
                              hipStream_t stream) {
    const float* x   = (const float*)d_in[0];
    const int*   ei  = (const int*)d_in[1];
    const float* W1l = (const float*)d_in[2];
    const float* W1r = (const float*)d_in[3];
    const float* b1  = (const float*)d_in[4];
    const float* W2l = (const float*)d_in[5];
    const float* W2r = (const float*)d_in[6];
    const float* b2  = (const float*)d_in[7];
    const float* W3l = (const float*)d_in[8];
    const float* W3r = (const float*)d_in[9];
    const float* b3  = (const float*)d_in[10];
    float* out = (float*)d_out;
    const int* src = ei;
    const int* dst = ei + NE;

    // ---- workspace layout ----
    int* deg    = (int*)d_ws;                     // 102400
    int* rowptr = deg + 102400;
    int* cursor = rowptr + 102400;
    int* csr    = cursor + 102400;                // 655360
    int* bsum   = csr + 655360;                   // 128
    int* boff   = bsum + 128;                     // 128
    bf16_t* W1h  = (bf16_t*)(boff + 128);         // 65536 bf16 each
    bf16_t* W1lo = W1h + 65536;
    bf16_t* W2h  = W1lo + 65536;
    bf16_t* W2lo = W2h + 65536;
    float* aggA = (float*)(W2lo + 65536);         // 12.8M f32 (layer-1 agg)
    float* h1   = aggA + 12800000;                // NN*256 f32 (reused as h2)
    float* C2   = h1 + (size_t)MPAD2 * 256;       // NN*256 f32
    float* q3   = C2 + (size_t)MPAD2 * 256;       // 200000
    float* h2   = h1;                             // reuse after L2 GEMM consumed h1

    // ---- CSR build (multi-block scan) ----
    hipMemsetAsync(deg, 0, NN * sizeof(int), stream);
    k_hist<<<(NE + 255) / 256, 256, 0, stream>>>(dst, deg);
    k_bsum<<<NBLK, 1024, 0, stream>>>(deg, bsum);
    k_bscan<<<1, 64, 0, stream>>>(bsum, boff, rowptr);
    k_scan2<<<NBLK, 1024, 0, stream>>>(deg, boff, rowptr, cursor);
    k_fill<<<(NE + 255) / 256, 256, 0, stream>>>(src, dst, cursor, csr);

    // ---- weight split ----
    k_split_w1<<<256, 256, 0, stream>>>(W1l, W1r, W1h, W1lo);
    k_split_w2<<<256, 256, 0, stream>>>(W2l, W2r, W2h, W2lo);

    // ---- layer 1 ----
    k_gather128s<<<(NN * 32 + 255) / 256, 256, 0, stream>>>(x, rowptr, csr, aggA);
    k_gemm_l1<<<MPAD2 / 128, 256, 0, stream>>>(aggA, x, W1h, W1lo, b1, h1);

    // ---- layer 2 (gather+combine+q3 fused) ----
    k_gemm_l2<<<MPAD2 / 128, 256, 0, stream>>>(h1, W2h, W2lo, C2);
    k_gather_combine<<<(NN * 32 + 255) / 256, 256, 0, stream>>>(C2, rowptr, csr, b2, W3l, h2, q3);

    // ---- layer 3 ----
    k_final<<<(NN + 255) / 256, 256, 0, stream>>>(h2, W3r, b3, q3, rowptr, csr, out);
}

// Round 10
// 433.568 us; speedup vs baseline: 1.2182x; 1.0556x over previous
//
#include <hip/hip_runtime.h>
#include <math.h>

#define NN 100000
#define NE 640000
#define MPAD2 100096  // NN rounded up to 128
#define NBLK 98       // ceil(NN / 1024)

typedef __bf16 bf16_t;
typedef bf16_t bf16x8 __attribute__((ext_vector_type(8)));
typedef float  f32x4  __attribute__((ext_vector_type(4)));

// ================= CSR build =================

__global__ __launch_bounds__(256) void k_hist(const int* __restrict__ dst,
                                              int* __restrict__ deg) {
    int e = blockIdx.x * 256 + threadIdx.x;
    if (e < NE) atomicAdd(&deg[dst[e]], 1);
}

__global__ __launch_bounds__(1024) void k_bsum(const int* __restrict__ deg,
                                               int* __restrict__ bsum) {
    __shared__ int warr[16];
    int t = threadIdx.x;
    int i = blockIdx.x * 1024 + t;
    int v = (i < NN) ? deg[i] : 0;
    int lane = t & 63, wid = t >> 6;
    #pragma unroll
    for (int off = 32; off > 0; off >>= 1) v += __shfl_xor(v, off, 64);
    if (lane == 0) warr[wid] = v;
    __syncthreads();
    if (t < 16) {
        int s = warr[t];
        #pragma unroll
        for (int off = 8; off > 0; off >>= 1) s += __shfl_xor(s, off, 64);
        if (t == 0) bsum[blockIdx.x] = s;
    }
}

__global__ __launch_bounds__(64) void k_bscan(const int* __restrict__ bsum,
        int* __restrict__ boff, int* __restrict__ rowptr) {
    int lane = threadIdx.x;
    int carry = 0;
    for (int base = 0; base < NBLK; base += 64) {
        int i = base + lane;
        int v = (i < NBLK) ? bsum[i] : 0;
        int s = v;
        #pragma unroll
        for (int off = 1; off < 64; off <<= 1) {
            int u = __shfl_up(s, off, 64);
            if (lane >= off) s += u;
        }
        if (i < NBLK) boff[i] = carry + s - v;
        carry += __shfl(s, 63, 64);
    }
    if (lane == 0) rowptr[NN] = NE;
}

__global__ __launch_bounds__(1024) void k_scan2(const int* __restrict__ deg,
        const int* __restrict__ boff, int* __restrict__ rowptr,
        int* __restrict__ cursor) {
    __shared__ int wsum[16];
    __shared__ int woff[16];
    int t = threadIdx.x;
    int lane = t & 63, wid = t >> 6;
    int i = blockIdx.x * 1024 + t;
    int v = (i < NN) ? deg[i] : 0;
    int s = v;
    #pragma unroll
    for (int off = 1; off < 64; off <<= 1) {
        int u = __shfl_up(s, off, 64);
        if (lane >= off) s += u;
    }
    if (lane == 63) wsum[wid] = s;
    __syncthreads();
    if (wid == 0) {
        int ws = (lane < 16) ? wsum[lane] : 0;
        #pragma unroll
        for (int off = 1; off < 16; off <<= 1) {
            int u = __shfl_up(ws, off, 64);
            if (lane >= off) ws += u;
        }
        if (lane < 16) woff[lane] = ws;
    }
    __syncthreads();
    if (i < NN) {
        int excl = boff[blockIdx.x] + (s - v) + (wid ? woff[wid - 1] : 0);
        rowptr[i] = excl;
        cursor[i] = excl;
    }
}

__global__ __launch_bounds__(256) void k_fill(const int* __restrict__ src,
        const int* __restrict__ dst, int* __restrict__ cursor,
        int* __restrict__ csr) {
    int e = blockIdx.x * 256 + threadIdx.x;
    if (e >= NE) return;
    int p = atomicAdd(&cursor[dst[e]], 1);
    csr[p] = src[e];
}

// ========== weight split (f32 -> hi/lo bf16) in MFMA B-fragment order ==========
// Wf layout: frag (ct, it) for col-tile ct (16 cols) and k-chunk it (32 k):
//   Wf[((ct*8 + it)*64 + lane)*8 + j] = W[col = ct*16 + (lane&15)]
//                                        [k   = it*32 + (lane>>4)*8 + j]
// -> in the GEMM, a wave's 64 lanes load CONSECUTIVE 16B chunks (1 KB coalesced
//    global_load_dwordx4), so W needs NO LDS staging at all.

__global__ __launch_bounds__(256) void k_split_w1(const float* __restrict__ W1l,
        const float* __restrict__ W1r, bf16_t* __restrict__ Wfh,
        bf16_t* __restrict__ Wfl) {
    int j = blockIdx.x, t = threadIdx.x;   // j = col (0..255), t = k (0..255)
    float f = (t < 128) ? W1l[j * 128 + t] : W1r[j * 128 + (t - 128)];
    bf16_t h = (bf16_t)f;
    bf16_t l = (bf16_t)(f - (float)h);
    int ct = j >> 4, l16 = j & 15;
    int it = t >> 5, quad = (t & 31) >> 3, jj = t & 7;
    int idx = ((ct * 8 + it) * 64 + quad * 16 + l16) * 8 + jj;
    Wfh[idx] = h;
    Wfl[idx] = l;
}

__global__ __launch_bounds__(256) void k_split_w2(const float* __restrict__ W2l,
        const float* __restrict__ W2r, bf16_t* __restrict__ Wfh,
        bf16_t* __restrict__ Wfl) {
    int j = blockIdx.x, t = threadIdx.x;
    float f = (j < 128) ? W2l[j * 256 + t] : W2r[(j - 128) * 256 + t];
    bf16_t h = (bf16_t)f;
    bf16_t l = (bf16_t)(f - (float)h);
    int ct = j >> 4, l16 = j & 15;
    int it = t >> 5, quad = (t & 31) >> 3, jj = t & 7;
    int idx = ((ct * 8 + it) * 64 + quad * 16 + l16) * 8 + jj;
    Wfh[idx] = h;
    Wfl[idx] = l;
}

// ================= gather-mean for layer 1 (f32, 128 wide) =================

__global__ __launch_bounds__(256) void k_gather128s(const float* __restrict__ feat,
        const int* __restrict__ rowptr, const int* __restrict__ csr,
        float* __restrict__ agg) {
    int tid = blockIdx.x * 256 + threadIdx.x;
    int node = tid >> 5;
    if (node >= NN) return;
    int lane4 = (tid & 31) << 2;
    int beg = rowptr[node], end = rowptr[node + 1];
    float4 acc = make_float4(0.f, 0.f, 0.f, 0.f);
    int e = beg;
    for (; e + 1 < end; e += 2) {
        int s0 = csr[e], s1 = csr[e + 1];
        float4 v0 = *(const float4*)(feat + (size_t)s0 * 128 + lane4);
        float4 v1 = *(const float4*)(feat + (size_t)s1 * 128 + lane4);
        acc.x += v0.x + v1.x; acc.y += v0.y + v1.y;
        acc.z += v0.z + v1.z; acc.w += v0.w + v1.w;
    }
    if (e < end) {
        int s0 = csr[e];
        float4 v0 = *(const float4*)(feat + (size_t)s0 * 128 + lane4);
        acc.x += v0.x; acc.y += v0.y; acc.z += v0.z; acc.w += v0.w;
    }
    float iv = 1.0f / (float)max(end - beg, 1);
    acc.x *= iv; acc.y *= iv; acc.z *= iv; acc.w *= iv;
    *(float4*)(agg + (size_t)node * 128 + lane4) = acc;
}

// ================= split-bf16 MFMA GEMM, BM=128, W LDS-free =================
// C = A @ W^T, 3-term split: C ~= Ah*Wh + Al*Wh + Ah*Wl.
// LDS is a per-CU resource shared by 4 SIMDs (R9 post-mortem): with W+A both
// staged, per-CU LDS cost was ~3.7x the MFMA cost -> util capped ~17%.
// Here W frags come straight from global (frag-order layout, coalesced 1KB
// loads, 256KB L2-resident); only A goes through LDS:
// 20 LDS ops/wave-iter (4 writes + 16 reads) vs 36 before.

#define PADK 2

__device__ __forceinline__ void splitv(float4 v0, float4 v1,
                                       bf16x8& h, bf16x8& l) {
    float f[8] = {v0.x, v0.y, v0.z, v0.w, v1.x, v1.y, v1.z, v1.w};
    #pragma unroll
    for (int i = 0; i < 8; i++) {
        bf16_t hi = (bf16_t)f[i];
        h[i] = hi;
        l[i] = (bf16_t)(f[i] - (float)hi);
    }
}

// Layer-1 GEMM, A = [agg | x] (each M x 128); fused epilogue h1 = relu(l2norm(C+b1))
__global__ __launch_bounds__(256, 2) void k_gemm_l1(const float* __restrict__ Aa,
        const float* __restrict__ Ax, const bf16_t* __restrict__ Wfh,
        const bf16_t* __restrict__ Wfl, const float* __restrict__ bias,
        float* __restrict__ H) {
    __shared__ bf16_t sAh[128][32 + PADK], sAl[128][32 + PADK];
    __shared__ float pr[128][4];
    int t = threadIdx.x;
    int wave = t >> 6, lane = t & 63, quad = lane >> 4, l16 = lane & 15;
    int r0 = blockIdx.x * 128;
    f32x4 acc[8][4] = {};
    int arow = t >> 1, ahalf = (t & 1) * 16;   // A staging: row, 16-f32 half
    int grow = r0 + arow; if (grow >= NN) grow = NN - 1;
    for (int it = 0; it < 8; it++) {
        int k0 = it * 32;
        // W fragment loads: coalesced global, no LDS; 2 barriers of slack
        bf16x8 bh[4], bl[4];
        #pragma unroll
        for (int nt = 0; nt < 4; nt++) {
            size_t fo = (size_t)(((wave * 4 + nt) * 8 + it) * 64 + lane) * 8;
            bh[nt] = *(const bf16x8*)&Wfh[fo];
            bl[nt] = *(const bf16x8*)&Wfl[fo];
        }
        const float* Asrc = (k0 < 128) ? Aa : Ax;
        int kb = (k0 < 128) ? k0 : (k0 - 128);
        __syncthreads();   // prev iter's frag readers done
        {
            const float* p = &Asrc[(size_t)grow * 128 + kb + ahalf];
            bf16x8 h0, l0, h1, l1;
            splitv(*(const float4*)p, *(const float4*)(p + 4), h0, l0);
            splitv(*(const float4*)(p + 8), *(const float4*)(p + 12), h1, l1);
            *(bf16x8*)&sAh[arow][ahalf] = h0;
            *(bf16x8*)&sAh[arow][ahalf + 8] = h1;
            *(bf16x8*)&sAl[arow][ahalf] = l0;
            *(bf16x8*)&sAl[arow][ahalf + 8] = l1;
        }
        __syncthreads();
        #pragma unroll
        for (int mt = 0; mt < 8; mt++) {
            bf16x8 ah = *(bf16x8*)&sAh[mt * 16 + l16][quad * 8];
            bf16x8 al = *(bf16x8*)&sAl[mt * 16 + l16][quad * 8];
            #pragma unroll
            for (int nt = 0; nt < 4; nt++) {
                acc[mt][nt] = __builtin_amdgcn_mfma_f32_16x16x32_bf16(ah, bh[nt], acc[mt][nt], 0, 0, 0);
                acc[mt][nt] = __builtin_amdgcn_mfma_f32_16x16x32_bf16(al, bh[nt], acc[mt][nt], 0, 0, 0);
                acc[mt][nt] = __builtin_amdgcn_mfma_f32_16x16x32_bf16(ah, bl[nt], acc[mt][nt], 0, 0, 0);
            }
        }
    }
    // ---- fused epilogue: bias, row L2-norm across 256 cols, relu ----
    float bcol[4];
    #pragma unroll
    for (int nt = 0; nt < 4; nt++) bcol[nt] = bias[wave * 64 + nt * 16 + l16];
    #pragma unroll
    for (int mt = 0; mt < 8; mt++)
        #pragma unroll
        for (int nt = 0; nt < 4; nt++)
            #pragma unroll
            for (int rg = 0; rg < 4; rg++)
                acc[mt][nt][rg] += bcol[nt];
    float ss[8][4];
    #pragma unroll
    for (int mt = 0; mt < 8; mt++)
        #pragma unroll
        for (int rg = 0; rg < 4; rg++) {
            float s = 0.f;
            #pragma unroll
            for (int nt = 0; nt < 4; nt++) s += acc[mt][nt][rg] * acc[mt][nt][rg];
            #pragma unroll
            for (int off = 1; off < 16; off <<= 1) s += __shfl_xor(s, off, 64);
            ss[mt][rg] = s;
        }
    if (l16 == 0) {
        #pragma unroll
        for (int mt = 0; mt < 8; mt++)
            #pragma unroll
            for (int rg = 0; rg < 4; rg++)
                pr[mt * 16 + quad * 4 + rg][wave] = ss[mt][rg];
    }
    __syncthreads();
    #pragma unroll
    for (int mt = 0; mt < 8; mt++)
        #pragma unroll
        for (int rg = 0; rg < 4; rg++) {
            int lr = mt * 16 + quad * 4 + rg;
            int row = r0 + lr;
            if (row >= NN) continue;
            float tot = pr[lr][0] + pr[lr][1] + pr[lr][2] + pr[lr][3];
            float inv = 1.0f / fmaxf(sqrtf(tot), 1e-12f);
            #pragma unroll
            for (int nt = 0; nt < 4; nt++) {
                int col = wave * 64 + nt * 16 + l16;
                H[(size_t)row * 256 + col] = fmaxf(acc[mt][nt][rg] * inv, 0.f);
            }
        }
}

// Layer-2 GEMM: C2 = h1 @ [W2l;W2r]^T, plain f32 store, BM=128, W LDS-free
__global__ __launch_bounds__(256, 2) void k_gemm_l2(const float* __restrict__ A,
        const bf16_t* __restrict__ Wfh, const bf16_t* __restrict__ Wfl,
        float* __restrict__ C) {
    __shared__ bf16_t sAh[128][32 + PADK], sAl[128][32 + PADK];
    int t = threadIdx.x;
    int wave = t >> 6, lane = t & 63, quad = lane >> 4, l16 = lane & 15;
    int r0 = blockIdx.x * 128;
    f32x4 acc[8][4] = {};
    int arow = t >> 1, ahalf = (t & 1) * 16;
    int grow = r0 + arow; if (grow >= NN) grow = NN - 1;
    for (int it = 0; it < 8; it++) {
        int k0 = it * 32;
        bf16x8 bh[4], bl[4];
        #pragma unroll
        for (int nt = 0; nt < 4; nt++) {
            size_t fo = (size_t)(((wave * 4 + nt) * 8 + it) * 64 + lane) * 8;
            bh[nt] = *(const bf16x8*)&Wfh[fo];
            bl[nt] = *(const bf16x8*)&Wfl[fo];
        }
        __syncthreads();
        {
            const float* p = &A[(size_t)grow * 256 + k0 + ahalf];
            bf16x8 h0, l0, h1, l1;
            splitv(*(const float4*)p, *(const float4*)(p + 4), h0, l0);
            splitv(*(const float4*)(p + 8), *(const float4*)(p + 12), h1, l1);
            *(bf16x8*)&sAh[arow][ahalf] = h0;
            *(bf16x8*)&sAh[arow][ahalf + 8] = h1;
            *(bf16x8*)&sAl[arow][ahalf] = l0;
            *(bf16x8*)&sAl[arow][ahalf + 8] = l1;
        }
        __syncthreads();
        #pragma unroll
        for (int mt = 0; mt < 8; mt++) {
            bf16x8 ah = *(bf16x8*)&sAh[mt * 16 + l16][quad * 8];
            bf16x8 al = *(bf16x8*)&sAl[mt * 16 + l16][quad * 8];
            #pragma unroll
            for (int nt = 0; nt < 4; nt++) {
                acc[mt][nt] = __builtin_amdgcn_mfma_f32_16x16x32_bf16(ah, bh[nt], acc[mt][nt], 0, 0, 0);
                acc[mt][nt] = __builtin_amdgcn_mfma_f32_16x16x32_bf16(al, bh[nt], acc[mt][nt], 0, 0, 0);
                acc[mt][nt] = __builtin_amdgcn_mfma_f32_16x16x32_bf16(ah, bl[nt], acc[mt][nt], 0, 0, 0);
            }
        }
    }
    #pragma unroll
    for (int mt = 0; mt < 8; mt++)
        #pragma unroll
        for (int rg = 0; rg < 4; rg++) {
            int row = r0 + mt * 16 + quad * 4 + rg;
            if (row >= NN) continue;
            #pragma unroll
            for (int nt = 0; nt < 4; nt++) {
                int col = wave * 64 + nt * 16 + l16;
                C[(size_t)row * 256 + col] = acc[mt][nt][rg];
            }
        }
}

// ==== fused layer-2 tail: gather-mean p2 + combine + norm + q3 ====

__global__ __launch_bounds__(256) void k_gather_combine(const float* __restrict__ C2,
        const int* __restrict__ rowptr, const int* __restrict__ csr,
        const float* __restrict__ b2, const float* __restrict__ W3l,
        float* __restrict__ h2, float* __restrict__ q3) {
    __shared__ float sw[256];
    int t = threadIdx.x;
    sw[t] = W3l[t];
    __syncthreads();
    int tid = blockIdx.x * 256 + t;
    int node = tid >> 5;
    if (node >= NN) return;
    int l = tid & 31;
    int lane4 = l << 2;
    int beg = rowptr[node], end = rowptr[node + 1];
    float4 acc = make_float4(0.f, 0.f, 0.f, 0.f);
    int e = beg;
    for (; e + 1 < end; e += 2) {
        int s0 = csr[e], s1 = csr[e + 1];
        float4 v0 = *(const float4*)(C2 + (size_t)s0 * 256 + lane4);
        float4 v1 = *(const float4*)(C2 + (size_t)s1 * 256 + lane4);
        acc.x += v0.x + v1.x; acc.y += v0.y + v1.y;
        acc.z += v0.z + v1.z; acc.w += v0.w + v1.w;
    }
    if (e < end) {
        int s0 = csr[e];
        float4 v0 = *(const float4*)(C2 + (size_t)s0 * 256 + lane4);
        acc.x += v0.x; acc.y += v0.y; acc.z += v0.z; acc.w += v0.w;
    }
    float iv = 1.0f / (float)max(end - beg, 1);
    float4 r = *(const float4*)&C2[(size_t)node * 256 + 128 + lane4];
    float4 b = *(const float4*)&b2[lane4];
    float v0 = acc.x * iv + r.x + b.x;
    float v1 = acc.y * iv + r.y + b.y;
    float v2 = acc.z * iv + r.z + b.z;
    float v3 = acc.w * iv + r.w + b.w;
    float s = v0 * v0 + v1 * v1 + v2 * v2 + v3 * v3;
    #pragma unroll
    for (int off = 16; off > 0; off >>= 1) s += __shfl_xor(s, off, 64);
    float invn = 1.0f / fmaxf(sqrtf(s), 1e-12f);
    float4 o;
    o.x = fmaxf(v0 * invn, 0.f); o.y = fmaxf(v1 * invn, 0.f);
    o.z = fmaxf(v2 * invn, 0.f); o.w = fmaxf(v3 * invn, 0.f);
    *(float4*)&h2[(size_t)node * 128 + lane4] = o;
    float a0 = o.x * sw[lane4] + o.y * sw[lane4+1] + o.z * sw[lane4+2] + o.w * sw[lane4+3];
    float a1 = o.x * sw[128+lane4] + o.y * sw[129+lane4] + o.z * sw[130+lane4] + o.w * sw[131+lane4];
    #pragma unroll
    for (int off = 16; off > 0; off >>= 1) {
        a0 += __shfl_xor(a0, off, 64);
        a1 += __shfl_xor(a1, off, 64);
    }
    if (l == 0) {
        q3[2 * node] = a0;
        q3[2 * node + 1] = a1;
    }
}

// ================= final (absorbs the 2-wide q3 gather) =================

__global__ __launch_bounds__(256) void k_final(const float* __restrict__ h2,
        const float* __restrict__ W3r, const float* __restrict__ b3,
        const float* __restrict__ q3, const int* __restrict__ rowptr,
        const int* __restrict__ csr, float* __restrict__ out) {
    __shared__ float sw[256];
    int t = threadIdx.x;
    sw[t] = W3r[t];
    __syncthreads();
    int i = blockIdx.x * 256 + t;
    if (i >= NN) return;
    int beg = rowptr[i], end = rowptr[i + 1];
    float g0 = 0.f, g1 = 0.f;
    for (int e = beg; e < end; e++) {
        int s = csr[e];
        g0 += q3[2 * s];
        g1 += q3[2 * s + 1];
    }
    float ivd = 1.0f / (float)max(end - beg, 1);
    g0 *= ivd; g1 *= ivd;
    const float4* row = (const float4*)(h2 + (size_t)i * 128);
    float a0 = 0.f, a1 = 0.f;
    #pragma unroll
    for (int q = 0; q < 32; q++) {
        float4 v = row[q];
        a0 += v.x * sw[4*q] + v.y * sw[4*q+1] + v.z * sw[4*q+2] + v.w * sw[4*q+3];
        a1 += v.x * sw[128+4*q] + v.y * sw[129+4*q] + v.z * sw[130+4*q] + v.w * sw[131+4*q];
    }
    float v0 = g0 + a0 + b3[0];
    float v1 = g1 + a1 + b3[1];
    float invn = 1.0f / fmaxf(sqrtf(v0 * v0 + v1 * v1), 1e-12f);
    v0 *= invn; v1 *= invn;
    float mx = fmaxf(v0, v1);
    float l = logf(expf(v0 - mx) + expf(v1 - mx));
    out[2 * i] = v0 - mx - l;
    out[2 * i + 1] = v1 - mx - l;
}

// ================= launch =================

extern "C" void kernel_launch(void* const* d_in, const int* in_sizes, int n_in,
                              void* d_out, int out_size, void* d_ws, size_t ws_size,
                              hipStream_t stream) {
    const float* x   = (const float*)d_in[0];
    const int*   ei  = (const int*)d_in[1];
    const float* W1l = (const float*)d_in[2];
    const float* W1r = (const float*)d_in[3];
    const float* b1  = (const float*)d_in[4];
    const float* W2l = (const float*)d_in[5];
    const float* W2r = (const float*)d_in[6];
    const float* b2  = (const float*)d_in[7];
    const float* W3l = (const float*)d_in[8];
    const float* W3r = (const float*)d_in[9];
    const float* b3  = (const float*)d_in[10];
    float* out = (float*)d_out;
    const int* src = ei;
    const int* dst = ei + NE;

    // ---- workspace layout ----
    int* deg    = (int*)d_ws;                     // 102400
    int* rowptr = deg + 102400;
    int* cursor = rowptr + 102400;
    int* csr    = cursor + 102400;                // 655360
    int* bsum   = csr + 655360;                   // 128
    int* boff   = bsum + 128;                     // 128
    bf16_t* W1h  = (bf16_t*)(boff + 128);         // 65536 bf16 each (frag order)
    bf16_t* W1lo = W1h + 65536;
    bf16_t* W2h  = W1lo + 65536;
    bf16_t* W2lo = W2h + 65536;
    float* aggA = (float*)(W2lo + 65536);         // 12.8M f32 (layer-1 agg)
    float* h1   = aggA + 12800000;                // NN*256 f32 (reused as h2)
    float* C2   = h1 + (size_t)MPAD2 * 256;       // NN*256 f32
    float* q3   = C2 + (size_t)MPAD2 * 256;       // 200000
    float* h2   = h1;                             // reuse after L2 GEMM consumed h1

    // ---- CSR build (multi-block scan) ----
    hipMemsetAsync(deg, 0, NN * sizeof(int), stream);
    k_hist<<<(NE + 255) / 256, 256, 0, stream>>>(dst, deg);
    k_bsum<<<NBLK, 1024, 0, stream>>>(deg, bsum);
    k_bscan<<<1, 64, 0, stream>>>(bsum, boff, rowptr);
    k_scan2<<<NBLK, 1024, 0, stream>>>(deg, boff, rowptr, cursor);
    k_fill<<<(NE + 255) / 256, 256, 0, stream>>>(src, dst, cursor, csr);

    // ---- weight split (fragment order) ----
    k_split_w1<<<256, 256, 0, stream>>>(W1l, W1r, W1h, W1lo);
    k_split_w2<<<256, 256, 0, stream>>>(W2l, W2r, W2h, W2lo);

    // ---- layer 1 ----
    k_gather128s<<<(NN * 32 + 255) / 256, 256, 0, stream>>>(x, rowptr, csr, aggA);
    k_gemm_l1<<<MPAD2 / 128, 256, 0, stream>>>(aggA, x, W1h, W1lo, b1, h1);

    // ---- layer 2 (gather+combine+q3 fused) ----
    k_gemm_l2<<<MPAD2 / 128, 256, 0, stream>>>(h1, W2h, W2lo, C2);
    k_gather_combine<<<(NN * 32 + 255) / 256, 256, 0, stream>>>(C2, rowptr, csr, b2, W3l, h2, q3);

    // ---- layer 3 ----
    k_final<<<(NN + 255) / 256, 256, 0, stream>>>(h2, W3r, b3, q3, rowptr, csr, out);
}